// Round 3
// baseline (956.789 us; speedup 1.0000x reference)
//
#include <hip/hip_runtime.h>

#define NG 72

// WIN(E,O,r,c): window element at row r, col c from de-interleaved even/odd arrays
#define WIN(E, O, r, c) (((c) & 1) ? (O)[(r)][(c) >> 1] : (E)[(r)][(c) >> 1])

// ---------------- conv1: (64,216,46,46) -> k5 g72 (3->8) -> relu -> pool2 -> (64,576,21,21)
__global__ __launch_bounds__(256, 4) void conv1_k(const float* __restrict__ x,
                                                  const float* __restrict__ w,
                                                  const float* __restrict__ bias,
                                                  float* __restrict__ out) {
  const int b = blockIdx.x / NG, g = blockIdx.x % NG;
  __shared__ float sxe[3][46][25];   // even cols (23 used), odd pitch
  __shared__ float sxo[3][46][25];   // odd cols
  __shared__ float sw[8 * 3 * 28];   // per-(oc,ic) padded 25->28, float4-aligned
  __shared__ float sb[8];
  const float* xp = x + (size_t)(b * 216 + g * 3) * 2116;
  const float4* xp4 = (const float4*)xp;   // 3*2116 = 6348 = 1587 float4, 16B-aligned
  for (int i = threadIdx.x; i < 1587; i += 256) {
    const float4 v = xp4[i];
#pragma unroll
    for (int j = 0; j < 4; j++) {
      const int k = 4 * i + j;
      const int ic = k / 2116, rem = k % 2116, r = rem / 46, c = rem % 46;
      const float f = (&v.x)[j];
      if (c & 1) sxo[ic][r][c >> 1] = f; else sxe[ic][r][c >> 1] = f;
    }
  }
  const float* wp = w + (size_t)(g * 8) * 75;
  for (int i = threadIdx.x; i < 600; i += 256) {
    const int oc = i / 75, rem = i % 75, ic = rem / 25, k = rem % 25;
    sw[(oc * 3 + ic) * 28 + k] = wp[i];
  }
  if (threadIdx.x < 8) sb[threadIdx.x] = bias[g * 8 + threadIdx.x];
  __syncthreads();
  for (int p = threadIdx.x; p < 441; p += 256) {
    const int py = p / 21, px = p % 21, iy = 2 * py;
    float acc[8][4];
#pragma unroll
    for (int o = 0; o < 8; o++)
#pragma unroll
      for (int q = 0; q < 4; q++) acc[o][q] = 0.f;
#pragma unroll
    for (int ic = 0; ic < 3; ic++) {
      float we[6][3], wo[6][3];
#pragma unroll
      for (int r = 0; r < 6; r++)
#pragma unroll
        for (int j = 0; j < 3; j++) {
          we[r][j] = sxe[ic][iy + r][px + j];
          wo[r][j] = sxo[ic][iy + r][px + j];
        }
#pragma unroll
      for (int oc = 0; oc < 8; oc++) {
        const float4* wq = (const float4*)&sw[(oc * 3 + ic) * 28];
#pragma unroll
        for (int q = 0; q < 7; q++) {
          const float4 w4 = wq[q];   // broadcast LDS read, conflict-free
#pragma unroll
          for (int j = 0; j < 4; j++) {
            const int k = 4 * q + j;
            if (k < 25) {
              const int ky = k / 5, kx = k % 5;
              const float wv_ = (&w4.x)[j];
              acc[oc][0] = fmaf(WIN(we, wo, ky,     kx),     wv_, acc[oc][0]);
              acc[oc][1] = fmaf(WIN(we, wo, ky,     kx + 1), wv_, acc[oc][1]);
              acc[oc][2] = fmaf(WIN(we, wo, ky + 1, kx),     wv_, acc[oc][2]);
              acc[oc][3] = fmaf(WIN(we, wo, ky + 1, kx + 1), wv_, acc[oc][3]);
            }
          }
        }
      }
    }
#pragma unroll
    for (int oc = 0; oc < 8; oc++) {
      const float v = fmaxf(fmaxf(acc[oc][0], acc[oc][1]), fmaxf(acc[oc][2], acc[oc][3])) + sb[oc];
      out[(size_t)(b * 576 + g * 8 + oc) * 441 + p] = fmaxf(v, 0.f);
    }
  }
}

// ---------------- conv2: (64,576,21,21) -> k3 (8->16) -> relu -> pool2 -> (64,1152,9,9)
#define C2_NBB 3
__global__ __launch_bounds__(256, 4) void conv2_k(const float* __restrict__ x,
                                                  const float* __restrict__ w,
                                                  const float* __restrict__ bias,
                                                  float* __restrict__ out) {
  const int g = blockIdx.x % NG, b0 = (blockIdx.x / NG) * C2_NBB;
  const int nbb = min(C2_NBB, 64 - b0);
  __shared__ float sx[C2_NBB][8][21][22];  // pitch 22: stride-2 lane reads = 2-way = free
  __shared__ float sw[16 * 8 * 9];
  __shared__ float sb[16];
  for (int bb = 0; bb < nbb; bb++) {
    const float* xp = x + (size_t)((b0 + bb) * 576 + g * 8) * 441;
    for (int i = threadIdx.x; i < 8 * 441; i += 256) {
      const int ic = i / 441, rem = i % 441, r = rem / 21, c = rem % 21;
      sx[bb][ic][r][c] = xp[i];
    }
  }
  const float* wp = w + (size_t)(g * 16) * 72;
  for (int i = threadIdx.x; i < 16 * 72; i += 256) sw[i] = wp[i];
  if (threadIdx.x < 16) sb[threadIdx.x] = bias[g * 16 + threadIdx.x];
  __syncthreads();
  for (int u = threadIdx.x; u < nbb * 81; u += 256) {
    const int bb = u / 81, p = u % 81, py = p / 9, px = p % 9;
    const int iy = 2 * py, ix = 2 * px;
    float acc[16][4];
#pragma unroll
    for (int o = 0; o < 16; o++)
#pragma unroll
      for (int q = 0; q < 4; q++) acc[o][q] = 0.f;
#pragma unroll
    for (int ic = 0; ic < 8; ic++) {
      float win[4][4];
#pragma unroll
      for (int r = 0; r < 4; r++)
#pragma unroll
        for (int c = 0; c < 4; c++) win[r][c] = sx[bb][ic][iy + r][ix + c];
#pragma unroll
      for (int oc = 0; oc < 16; oc++) {
        const float* wq = &sw[(oc * 8 + ic) * 9];
#pragma unroll
        for (int ky = 0; ky < 3; ky++)
#pragma unroll
          for (int kx = 0; kx < 3; kx++) {
            const float wv_ = wq[ky * 3 + kx];   // broadcast
            acc[oc][0] = fmaf(win[ky][kx],         wv_, acc[oc][0]);
            acc[oc][1] = fmaf(win[ky][kx + 1],     wv_, acc[oc][1]);
            acc[oc][2] = fmaf(win[ky + 1][kx],     wv_, acc[oc][2]);
            acc[oc][3] = fmaf(win[ky + 1][kx + 1], wv_, acc[oc][3]);
          }
      }
    }
#pragma unroll
    for (int oc = 0; oc < 16; oc++) {
      const float v = fmaxf(fmaxf(acc[oc][0], acc[oc][1]), fmaxf(acc[oc][2], acc[oc][3])) + sb[oc];
      out[(size_t)((b0 + bb) * 1152 + g * 16 + oc) * 81 + p] = fmaxf(v, 0.f);
    }
  }
}

// ---------------- conv3: (64,1152,9,9) -> k3 (16->32) -> relu -> pool2 -> (64,2304,3,3)
#define C3_NBB 7
__global__ __launch_bounds__(256, 4) void conv3_k(const float* __restrict__ x,
                                                  const float* __restrict__ w,
                                                  const float* __restrict__ bias,
                                                  float* __restrict__ out) {
  const int g = blockIdx.x % NG, b0 = (blockIdx.x / NG) * C3_NBB;
  const int nbb = min(C3_NBB, 64 - b0);
  __shared__ float sx[C3_NBB][16][81];
  __shared__ float sw[32 * 16 * 9];
  __shared__ float sb[32];
  for (int bb = 0; bb < nbb; bb++) {
    const float* xp = x + (size_t)((b0 + bb) * 1152 + g * 16) * 81;
    for (int i = threadIdx.x; i < 16 * 81; i += 256) sx[bb][i / 81][i % 81] = xp[i];
  }
  const float* wp = w + (size_t)(g * 32) * 144;
  for (int i = threadIdx.x; i < 32 * 144; i += 256) sw[i] = wp[i];
  if (threadIdx.x < 32) sb[threadIdx.x] = bias[g * 32 + threadIdx.x];
  __syncthreads();
  for (int u = threadIdx.x; u < nbb * 36; u += 256) {
    const int bb = u / 36, rem = u % 36, ocg = rem / 9, p = rem % 9;
    const int py = p / 3, px = p % 3, iy = 2 * py, ix = 2 * px;
    float acc[8][4];
#pragma unroll
    for (int o = 0; o < 8; o++)
#pragma unroll
      for (int q = 0; q < 4; q++) acc[o][q] = 0.f;
#pragma unroll
    for (int ic = 0; ic < 16; ic++) {
      float win[4][4];
#pragma unroll
      for (int r = 0; r < 4; r++)
#pragma unroll
        for (int c = 0; c < 4; c++) win[r][c] = sx[bb][ic][(iy + r) * 9 + ix + c];
#pragma unroll
      for (int o8 = 0; o8 < 8; o8++) {
        const int oc = ocg * 8 + o8;
        const float* wq = &sw[(oc * 16 + ic) * 9];
#pragma unroll
        for (int ky = 0; ky < 3; ky++)
#pragma unroll
          for (int kx = 0; kx < 3; kx++) {
            const float wv_ = wq[ky * 3 + kx];   // broadcast
            acc[o8][0] = fmaf(win[ky][kx],         wv_, acc[o8][0]);
            acc[o8][1] = fmaf(win[ky][kx + 1],     wv_, acc[o8][1]);
            acc[o8][2] = fmaf(win[ky + 1][kx],     wv_, acc[o8][2]);
            acc[o8][3] = fmaf(win[ky + 1][kx + 1], wv_, acc[o8][3]);
          }
      }
    }
#pragma unroll
    for (int o8 = 0; o8 < 8; o8++) {
      const int oc = ocg * 8 + o8;
      const float v = fmaxf(fmaxf(acc[o8][0], acc[o8][1]), fmaxf(acc[o8][2], acc[o8][3])) + sb[oc];
      out[(size_t)((b0 + bb) * 2304 + g * 32 + oc) * 9 + p] = fmaxf(v, 0.f);
    }
  }
}

// ---------------- fused block-diagonal linear1 (288->64) + linear2 (64->2) + bias
__global__ __launch_bounds__(256) void lin_k(const float* __restrict__ h,
                                             const float* __restrict__ w1,
                                             const float* __restrict__ w2,
                                             const float* __restrict__ b2,
                                             float* __restrict__ out) {
  const int g = blockIdx.x % NG, b0 = (blockIdx.x / NG) * 32;
  __shared__ float sw1[64 * 292];
  __shared__ float sf[32 * 300];
  __shared__ float so[32 * 65];
  __shared__ float sw2[2 * 64];
  __shared__ float sb2[2];
  for (int i = threadIdx.x; i < 64 * 288; i += 256) {
    const int o = i / 288, k = i % 288;
    sw1[o * 292 + k] = w1[(size_t)(g * 64 + o) * 20736 + g * 288 + k];
  }
  for (int i = threadIdx.x; i < 32 * 288; i += 256) {
    const int bb = i / 288, k = i % 288;
    sf[bb * 300 + k] = h[(size_t)(b0 + bb) * 20736 + g * 288 + k];
  }
  if (threadIdx.x < 128) {
    const int j = threadIdx.x >> 6, o = threadIdx.x & 63;
    sw2[j * 64 + o] = w2[(size_t)(g * 2 + j) * 4608 + g * 64 + o];
  }
  if (threadIdx.x < 2) sb2[threadIdx.x] = b2[g * 2 + threadIdx.x];
  __syncthreads();
  const int bp = threadIdx.x & 15, oq = threadIdx.x >> 4;
  const int o0 = 4 * oq;
  float acc[2][4];
#pragma unroll
  for (int i = 0; i < 2; i++)
#pragma unroll
    for (int j = 0; j < 4; j++) acc[i][j] = 0.f;
  for (int k4 = 0; k4 < 72; k4++) {
    const float4 f0 = *(const float4*)&sf[bp * 300 + 4 * k4];
    const float4 f1 = *(const float4*)&sf[(bp + 16) * 300 + 4 * k4];
#pragma unroll
    for (int j = 0; j < 4; j++) {
      const float4 wr = *(const float4*)&sw1[(o0 + j) * 292 + 4 * k4];
      acc[0][j] = fmaf(f0.x, wr.x, fmaf(f0.y, wr.y, fmaf(f0.z, wr.z, fmaf(f0.w, wr.w, acc[0][j]))));
      acc[1][j] = fmaf(f1.x, wr.x, fmaf(f1.y, wr.y, fmaf(f1.z, wr.z, fmaf(f1.w, wr.w, acc[1][j]))));
    }
  }
#pragma unroll
  for (int j = 0; j < 4; j++) {
    so[bp * 65 + o0 + j] = acc[0][j];
    so[(bp + 16) * 65 + o0 + j] = acc[1][j];
  }
  __syncthreads();
  if (threadIdx.x < 64) {
    const int bb = threadIdx.x >> 1, j = threadIdx.x & 1;
    float a = sb2[j];
#pragma unroll 8
    for (int o = 0; o < 64; o++) a = fmaf(so[bb * 65 + o], sw2[j * 64 + o], a);
    out[(b0 + bb) * 144 + g * 2 + j] = a;
  }
}

extern "C" void kernel_launch(void* const* d_in, const int* in_sizes, int n_in,
                              void* d_out, int out_size, void* d_ws, size_t ws_size,
                              hipStream_t stream) {
  const float* x   = (const float*)d_in[0];
  const float* w1  = (const float*)d_in[1];
  const float* b1  = (const float*)d_in[2];
  const float* w2  = (const float*)d_in[3];
  const float* b2  = (const float*)d_in[4];
  const float* w3  = (const float*)d_in[5];
  const float* b3  = (const float*)d_in[6];
  const float* l1w = (const float*)d_in[7];
  const float* l2w = (const float*)d_in[8];
  const float* l2b = (const float*)d_in[9];
  float* out = (float*)d_out;

  float* h1 = (float*)d_ws;          // 64*576*21*21
  float* h2 = h1 + 16257024;         // 64*1152*9*9
  float* h3 = h2 + 5971968;          // 64*2304*3*3

  conv1_k<<<dim3(64 * NG), 256, 0, stream>>>(x,  w1, b1, h1);
  conv2_k<<<dim3(22 * NG), 256, 0, stream>>>(h1, w2, b2, h2);
  conv3_k<<<dim3(10 * NG), 256, 0, stream>>>(h2, w3, b3, h3);
  lin_k  <<<dim3(2 * NG),  256, 0, stream>>>(h3, l1w, l2w, l2b, out);
}

// Round 4
// 659.414 us; speedup vs baseline: 1.4510x; 1.4510x over previous
//
#include <hip/hip_runtime.h>

#define NG 72

// WIN(E,O,r,c): window element at row r, col c from de-interleaved even/odd arrays
#define WIN(E, O, r, c) (((c) & 1) ? (O)[(r)][(c) >> 1] : (E)[(r)][(c) >> 1])

// ---------------- conv1: (64,216,46,46) -> k5 g72 (3->8) -> relu -> pool2 -> (64,576,21,21)
__global__ __launch_bounds__(256, 2) void conv1_k(const float* __restrict__ x,
                                                  const float* __restrict__ w,
                                                  const float* __restrict__ bias,
                                                  float* __restrict__ out) {
  const int b = blockIdx.x / NG, g = blockIdx.x % NG;
  __shared__ float sxe[3][46][25];   // even cols (23 used), odd pitch
  __shared__ float sxo[3][46][25];   // odd cols
  __shared__ float sw[8 * 3 * 28];   // per-(oc,ic) padded 25->28, float4-aligned
  __shared__ float sb[8];
  const float* xp = x + (size_t)(b * 216 + g * 3) * 2116;
  const float4* xp4 = (const float4*)xp;   // 3*2116 = 6348 = 1587 float4
  for (int i = threadIdx.x; i < 1587; i += 256) {
    const float4 v = xp4[i];
#pragma unroll
    for (int j = 0; j < 4; j++) {
      const int k = 4 * i + j;
      const int ic = k / 2116, rem = k % 2116, r = rem / 46, c = rem % 46;
      const float f = (&v.x)[j];
      if (c & 1) sxo[ic][r][c >> 1] = f; else sxe[ic][r][c >> 1] = f;
    }
  }
  const float* wp = w + (size_t)(g * 8) * 75;
  for (int i = threadIdx.x; i < 600; i += 256) {
    const int oc = i / 75, rem = i % 75, ic = rem / 25, k = rem % 25;
    sw[(oc * 3 + ic) * 28 + k] = wp[i];
  }
  if (threadIdx.x < 8) sb[threadIdx.x] = bias[g * 8 + threadIdx.x];
  __syncthreads();
  for (int p = threadIdx.x; p < 441; p += 256) {
    const int py = p / 21, px = p % 21, iy = 2 * py;
    float acc[8][4];
#pragma unroll
    for (int o = 0; o < 8; o++)
#pragma unroll
      for (int q = 0; q < 4; q++) acc[o][q] = 0.f;
#pragma unroll
    for (int ic = 0; ic < 3; ic++) {
      float we[6][3], wo[6][3];
#pragma unroll
      for (int r = 0; r < 6; r++)
#pragma unroll
        for (int j = 0; j < 3; j++) {
          we[r][j] = sxe[ic][iy + r][px + j];
          wo[r][j] = sxo[ic][iy + r][px + j];
        }
#pragma unroll
      for (int oc = 0; oc < 8; oc++) {
        const float4* wq = (const float4*)&sw[(oc * 3 + ic) * 28];
#pragma unroll
        for (int q = 0; q < 7; q++) {
          const float4 w4 = wq[q];   // broadcast LDS read, conflict-free
#pragma unroll
          for (int j = 0; j < 4; j++) {
            const int k = 4 * q + j;
            if (k < 25) {
              const int ky = k / 5, kx = k % 5;
              const float wv_ = (&w4.x)[j];
              acc[oc][0] = fmaf(WIN(we, wo, ky,     kx),     wv_, acc[oc][0]);
              acc[oc][1] = fmaf(WIN(we, wo, ky,     kx + 1), wv_, acc[oc][1]);
              acc[oc][2] = fmaf(WIN(we, wo, ky + 1, kx),     wv_, acc[oc][2]);
              acc[oc][3] = fmaf(WIN(we, wo, ky + 1, kx + 1), wv_, acc[oc][3]);
            }
          }
        }
      }
    }
#pragma unroll
    for (int oc = 0; oc < 8; oc++) {
      const float v = fmaxf(fmaxf(acc[oc][0], acc[oc][1]), fmaxf(acc[oc][2], acc[oc][3])) + sb[oc];
      out[(size_t)(b * 576 + g * 8 + oc) * 441 + p] = fmaxf(v, 0.f);
    }
  }
}

// ---------------- conv2: (64,576,21,21) -> k3 (8->16) -> relu -> pool2 -> (64,1152,9,9)
#define C2_NBB 3
__global__ __launch_bounds__(256, 2) void conv2_k(const float* __restrict__ x,
                                                  const float* __restrict__ w,
                                                  const float* __restrict__ bias,
                                                  float* __restrict__ out) {
  const int g = blockIdx.x % NG, b0 = (blockIdx.x / NG) * C2_NBB;
  const int nbb = min(C2_NBB, 64 - b0);
  __shared__ float sx[C2_NBB][8][21][22];  // pitch 22: stride-2 lane reads = 2-way = free
  __shared__ float sw[16 * 8 * 9];
  __shared__ float sb[16];
  for (int bb = 0; bb < nbb; bb++) {
    const float* xp = x + (size_t)((b0 + bb) * 576 + g * 8) * 441;
    for (int i = threadIdx.x; i < 8 * 441; i += 256) {
      const int ic = i / 441, rem = i % 441, r = rem / 21, c = rem % 21;
      sx[bb][ic][r][c] = xp[i];
    }
  }
  const float* wp = w + (size_t)(g * 16) * 72;
  for (int i = threadIdx.x; i < 16 * 72; i += 256) sw[i] = wp[i];
  if (threadIdx.x < 16) sb[threadIdx.x] = bias[g * 16 + threadIdx.x];
  __syncthreads();
  for (int u = threadIdx.x; u < nbb * 81; u += 256) {
    const int bb = u / 81, p = u % 81, py = p / 9, px = p % 9;
    const int iy = 2 * py, ix = 2 * px;
    // two passes of 8 oc to keep accumulator pressure low (32 regs)
#pragma unroll
    for (int half = 0; half < 2; half++) {
      float acc[8][4];
#pragma unroll
      for (int o = 0; o < 8; o++)
#pragma unroll
        for (int q = 0; q < 4; q++) acc[o][q] = 0.f;
#pragma unroll
      for (int ic = 0; ic < 8; ic++) {
        float win[4][4];
#pragma unroll
        for (int r = 0; r < 4; r++)
#pragma unroll
          for (int c = 0; c < 4; c++) win[r][c] = sx[bb][ic][iy + r][ix + c];
#pragma unroll
        for (int o8 = 0; o8 < 8; o8++) {
          const int oc = half * 8 + o8;
          const float* wq = &sw[(oc * 8 + ic) * 9];
#pragma unroll
          for (int ky = 0; ky < 3; ky++)
#pragma unroll
            for (int kx = 0; kx < 3; kx++) {
              const float wv_ = wq[ky * 3 + kx];   // broadcast
              acc[o8][0] = fmaf(win[ky][kx],         wv_, acc[o8][0]);
              acc[o8][1] = fmaf(win[ky][kx + 1],     wv_, acc[o8][1]);
              acc[o8][2] = fmaf(win[ky + 1][kx],     wv_, acc[o8][2]);
              acc[o8][3] = fmaf(win[ky + 1][kx + 1], wv_, acc[o8][3]);
            }
        }
      }
#pragma unroll
      for (int o8 = 0; o8 < 8; o8++) {
        const int oc = half * 8 + o8;
        const float v = fmaxf(fmaxf(acc[o8][0], acc[o8][1]), fmaxf(acc[o8][2], acc[o8][3])) + sb[oc];
        out[(size_t)((b0 + bb) * 1152 + g * 16 + oc) * 81 + p] = fmaxf(v, 0.f);
      }
    }
  }
}

// ---------------- conv3: (64,1152,9,9) -> k3 (16->32) -> relu -> pool2 -> (64,2304,3,3)
#define C3_NBB 7
__global__ __launch_bounds__(256, 2) void conv3_k(const float* __restrict__ x,
                                                  const float* __restrict__ w,
                                                  const float* __restrict__ bias,
                                                  float* __restrict__ out) {
  const int g = blockIdx.x % NG, b0 = (blockIdx.x / NG) * C3_NBB;
  const int nbb = min(C3_NBB, 64 - b0);
  __shared__ float sx[C3_NBB][16][81];
  __shared__ float sw[32 * 16 * 9];
  __shared__ float sb[32];
  for (int bb = 0; bb < nbb; bb++) {
    const float* xp = x + (size_t)((b0 + bb) * 1152 + g * 16) * 81;
    for (int i = threadIdx.x; i < 16 * 81; i += 256) sx[bb][i / 81][i % 81] = xp[i];
  }
  const float* wp = w + (size_t)(g * 32) * 144;
  for (int i = threadIdx.x; i < 32 * 144; i += 256) sw[i] = wp[i];
  if (threadIdx.x < 32) sb[threadIdx.x] = bias[g * 32 + threadIdx.x];
  __syncthreads();
  for (int u = threadIdx.x; u < nbb * 36; u += 256) {
    const int bb = u / 36, rem = u % 36, ocg = rem / 9, p = rem % 9;
    const int py = p / 3, px = p % 3, iy = 2 * py, ix = 2 * px;
    float acc[8][4];
#pragma unroll
    for (int o = 0; o < 8; o++)
#pragma unroll
      for (int q = 0; q < 4; q++) acc[o][q] = 0.f;
#pragma unroll
    for (int ic = 0; ic < 16; ic++) {
      float win[4][4];
#pragma unroll
      for (int r = 0; r < 4; r++)
#pragma unroll
        for (int c = 0; c < 4; c++) win[r][c] = sx[bb][ic][(iy + r) * 9 + ix + c];
#pragma unroll
      for (int o8 = 0; o8 < 8; o8++) {
        const int oc = ocg * 8 + o8;
        const float* wq = &sw[(oc * 16 + ic) * 9];
#pragma unroll
        for (int ky = 0; ky < 3; ky++)
#pragma unroll
          for (int kx = 0; kx < 3; kx++) {
            const float wv_ = wq[ky * 3 + kx];   // broadcast
            acc[o8][0] = fmaf(win[ky][kx],         wv_, acc[o8][0]);
            acc[o8][1] = fmaf(win[ky][kx + 1],     wv_, acc[o8][1]);
            acc[o8][2] = fmaf(win[ky + 1][kx],     wv_, acc[o8][2]);
            acc[o8][3] = fmaf(win[ky + 1][kx + 1], wv_, acc[o8][3]);
          }
      }
    }
#pragma unroll
    for (int o8 = 0; o8 < 8; o8++) {
      const int oc = ocg * 8 + o8;
      const float v = fmaxf(fmaxf(acc[o8][0], acc[o8][1]), fmaxf(acc[o8][2], acc[o8][3])) + sb[oc];
      out[(size_t)((b0 + bb) * 2304 + g * 32 + oc) * 9 + p] = fmaxf(v, 0.f);
    }
  }
}

// ---------------- fused block-diagonal linear1 (288->64) + linear2 (64->2) + bias
__global__ __launch_bounds__(256) void lin_k(const float* __restrict__ h,
                                             const float* __restrict__ w1,
                                             const float* __restrict__ w2,
                                             const float* __restrict__ b2,
                                             float* __restrict__ out) {
  const int g = blockIdx.x % NG, b0 = (blockIdx.x / NG) * 32;
  __shared__ float sw1[64 * 292];
  __shared__ float sf[32 * 300];
  __shared__ float so[32 * 65];
  __shared__ float sw2[2 * 64];
  __shared__ float sb2[2];
  for (int i = threadIdx.x; i < 64 * 288; i += 256) {
    const int o = i / 288, k = i % 288;
    sw1[o * 292 + k] = w1[(size_t)(g * 64 + o) * 20736 + g * 288 + k];
  }
  for (int i = threadIdx.x; i < 32 * 288; i += 256) {
    const int bb = i / 288, k = i % 288;
    sf[bb * 300 + k] = h[(size_t)(b0 + bb) * 20736 + g * 288 + k];
  }
  if (threadIdx.x < 128) {
    const int j = threadIdx.x >> 6, o = threadIdx.x & 63;
    sw2[j * 64 + o] = w2[(size_t)(g * 2 + j) * 4608 + g * 64 + o];
  }
  if (threadIdx.x < 2) sb2[threadIdx.x] = b2[g * 2 + threadIdx.x];
  __syncthreads();
  const int bp = threadIdx.x & 15, oq = threadIdx.x >> 4;
  const int o0 = 4 * oq;
  float acc[2][4];
#pragma unroll
  for (int i = 0; i < 2; i++)
#pragma unroll
    for (int j = 0; j < 4; j++) acc[i][j] = 0.f;
  for (int k4 = 0; k4 < 72; k4++) {
    const float4 f0 = *(const float4*)&sf[bp * 300 + 4 * k4];
    const float4 f1 = *(const float4*)&sf[(bp + 16) * 300 + 4 * k4];
#pragma unroll
    for (int j = 0; j < 4; j++) {
      const float4 wr = *(const float4*)&sw1[(o0 + j) * 292 + 4 * k4];
      acc[0][j] = fmaf(f0.x, wr.x, fmaf(f0.y, wr.y, fmaf(f0.z, wr.z, fmaf(f0.w, wr.w, acc[0][j]))));
      acc[1][j] = fmaf(f1.x, wr.x, fmaf(f1.y, wr.y, fmaf(f1.z, wr.z, fmaf(f1.w, wr.w, acc[1][j]))));
    }
  }
#pragma unroll
  for (int j = 0; j < 4; j++) {
    so[bp * 65 + o0 + j] = acc[0][j];
    so[(bp + 16) * 65 + o0 + j] = acc[1][j];
  }
  __syncthreads();
  if (threadIdx.x < 64) {
    const int bb = threadIdx.x >> 1, j = threadIdx.x & 1;
    float a = sb2[j];
#pragma unroll 8
    for (int o = 0; o < 64; o++) a = fmaf(so[bb * 65 + o], sw2[j * 64 + o], a);
    out[(b0 + bb) * 144 + g * 2 + j] = a;
  }
}

extern "C" void kernel_launch(void* const* d_in, const int* in_sizes, int n_in,
                              void* d_out, int out_size, void* d_ws, size_t ws_size,
                              hipStream_t stream) {
  const float* x   = (const float*)d_in[0];
  const float* w1  = (const float*)d_in[1];
  const float* b1  = (const float*)d_in[2];
  const float* w2  = (const float*)d_in[3];
  const float* b2  = (const float*)d_in[4];
  const float* w3  = (const float*)d_in[5];
  const float* b3  = (const float*)d_in[6];
  const float* l1w = (const float*)d_in[7];
  const float* l2w = (const float*)d_in[8];
  const float* l2b = (const float*)d_in[9];
  float* out = (float*)d_out;

  float* h1 = (float*)d_ws;          // 64*576*21*21
  float* h2 = h1 + 16257024;         // 64*1152*9*9
  float* h3 = h2 + 5971968;          // 64*2304*3*3

  conv1_k<<<dim3(64 * NG), 256, 0, stream>>>(x,  w1, b1, h1);
  conv2_k<<<dim3(22 * NG), 256, 0, stream>>>(h1, w2, b2, h2);
  conv3_k<<<dim3(10 * NG), 256, 0, stream>>>(h2, w3, b3, h3);
  lin_k  <<<dim3(2 * NG),  256, 0, stream>>>(h3, l1w, l2w, l2b, out);
}

// Round 5
// 398.874 us; speedup vs baseline: 2.3987x; 1.6532x over previous
//
#include <hip/hip_runtime.h>

#define NG 72

// WIN(E,O,r,c): window element at row r, col c from de-interleaved even/odd arrays
#define WIN(E, O, r, c) (((c) & 1) ? (O)[(r)][(c) >> 1] : (E)[(r)][(c) >> 1])

// ---------------- conv1: (64,216,46,46) -> k5 g72 (3->8) -> relu -> pool2 -> (64,576,21,21)
// 448 threads: one pooled position per thread (441 used). Two sequential 4-oc
// halves keep the live set ~80 VGPR (acc 16 + window 36) -> no spill, no cap.
__global__ __launch_bounds__(448) void conv1_k(const float* __restrict__ x,
                                               const float* __restrict__ w,
                                               const float* __restrict__ bias,
                                               float* __restrict__ out) {
  const int b = blockIdx.x / NG, g = blockIdx.x % NG;
  __shared__ float sxe[3][46][25];   // even cols (23 used), odd pitch
  __shared__ float sxo[3][46][25];   // odd cols
  __shared__ float sw[8 * 3 * 28];   // per-(oc,ic) padded 25->28, float4-aligned
  __shared__ float sb[8];
  const float* xp = x + (size_t)(b * 216 + g * 3) * 2116;
  const float4* xp4 = (const float4*)xp;   // 3*2116 = 6348 = 1587 float4
  for (int i = threadIdx.x; i < 1587; i += 448) {
    const float4 v = xp4[i];
#pragma unroll
    for (int j = 0; j < 4; j++) {
      const int k = 4 * i + j;
      const int ic = k / 2116, rem = k % 2116, r = rem / 46, c = rem % 46;
      const float f = (&v.x)[j];
      if (c & 1) sxo[ic][r][c >> 1] = f; else sxe[ic][r][c >> 1] = f;
    }
  }
  const float* wp = w + (size_t)(g * 8) * 75;
  for (int i = threadIdx.x; i < 600; i += 448) {
    const int oc = i / 75, rem = i % 75, ic = rem / 25, k = rem % 25;
    sw[(oc * 3 + ic) * 28 + k] = wp[i];
  }
  if (threadIdx.x < 8) sb[threadIdx.x] = bias[g * 8 + threadIdx.x];
  __syncthreads();
  const int p = threadIdx.x;
  if (p < 441) {
    const int py = p / 21, px = p % 21, iy = 2 * py;
#pragma unroll 1   // sequential halves: do NOT merge live ranges
    for (int half = 0; half < 2; half++) {
      float acc[4][4];
#pragma unroll
      for (int o = 0; o < 4; o++)
#pragma unroll
        for (int q = 0; q < 4; q++) acc[o][q] = 0.f;
#pragma unroll
      for (int ic = 0; ic < 3; ic++) {
        float we[6][3], wo[6][3];
#pragma unroll
        for (int r = 0; r < 6; r++)
#pragma unroll
          for (int j = 0; j < 3; j++) {
            we[r][j] = sxe[ic][iy + r][px + j];
            wo[r][j] = sxo[ic][iy + r][px + j];
          }
#pragma unroll
        for (int o4 = 0; o4 < 4; o4++) {
          const int oc = half * 4 + o4;
          const float4* wq = (const float4*)&sw[(oc * 3 + ic) * 28];
#pragma unroll
          for (int q = 0; q < 7; q++) {
            const float4 w4 = wq[q];   // broadcast LDS read, conflict-free
#pragma unroll
            for (int j = 0; j < 4; j++) {
              const int k = 4 * q + j;
              if (k < 25) {
                const int ky = k / 5, kx = k % 5;
                const float wv_ = (&w4.x)[j];
                acc[o4][0] = fmaf(WIN(we, wo, ky,     kx),     wv_, acc[o4][0]);
                acc[o4][1] = fmaf(WIN(we, wo, ky,     kx + 1), wv_, acc[o4][1]);
                acc[o4][2] = fmaf(WIN(we, wo, ky + 1, kx),     wv_, acc[o4][2]);
                acc[o4][3] = fmaf(WIN(we, wo, ky + 1, kx + 1), wv_, acc[o4][3]);
              }
            }
          }
        }
      }
#pragma unroll
      for (int o4 = 0; o4 < 4; o4++) {
        const int oc = half * 4 + o4;
        const float v = fmaxf(fmaxf(acc[o4][0], acc[o4][1]), fmaxf(acc[o4][2], acc[o4][3])) + sb[oc];
        out[(size_t)(b * 576 + g * 8 + oc) * 441 + p] = fmaxf(v, 0.f);
      }
    }
  }
}

// ---------------- conv2: (64,576,21,21) -> k3 (8->16) -> relu -> pool2 -> (64,1152,9,9)
#define C2_NBB 3
__global__ __launch_bounds__(256) void conv2_k(const float* __restrict__ x,
                                               const float* __restrict__ w,
                                               const float* __restrict__ bias,
                                               float* __restrict__ out) {
  const int g = blockIdx.x % NG, b0 = (blockIdx.x / NG) * C2_NBB;
  const int nbb = min(C2_NBB, 64 - b0);
  __shared__ float sx[C2_NBB][8][21][22];
  __shared__ float sw[16 * 8 * 9];
  __shared__ float sb[16];
  for (int bb = 0; bb < nbb; bb++) {
    const float* xp = x + (size_t)((b0 + bb) * 576 + g * 8) * 441;
    for (int i = threadIdx.x; i < 8 * 441; i += 256) {
      const int ic = i / 441, rem = i % 441, r = rem / 21, c = rem % 21;
      sx[bb][ic][r][c] = xp[i];
    }
  }
  const float* wp = w + (size_t)(g * 16) * 72;
  for (int i = threadIdx.x; i < 16 * 72; i += 256) sw[i] = wp[i];
  if (threadIdx.x < 16) sb[threadIdx.x] = bias[g * 16 + threadIdx.x];
  __syncthreads();
  for (int u = threadIdx.x; u < nbb * 81; u += 256) {
    const int bb = u / 81, p = u % 81, py = p / 9, px = p % 9;
    const int iy = 2 * py, ix = 2 * px;
#pragma unroll 1   // sequential halves
    for (int half = 0; half < 2; half++) {
      float acc[8][4];
#pragma unroll
      for (int o = 0; o < 8; o++)
#pragma unroll
        for (int q = 0; q < 4; q++) acc[o][q] = 0.f;
#pragma unroll
      for (int ic = 0; ic < 8; ic++) {
        float win[4][4];
#pragma unroll
        for (int r = 0; r < 4; r++)
#pragma unroll
          for (int c = 0; c < 4; c++) win[r][c] = sx[bb][ic][iy + r][ix + c];
#pragma unroll
        for (int o8 = 0; o8 < 8; o8++) {
          const int oc = half * 8 + o8;
          const float* wq = &sw[(oc * 8 + ic) * 9];
#pragma unroll
          for (int ky = 0; ky < 3; ky++)
#pragma unroll
            for (int kx = 0; kx < 3; kx++) {
              const float wv_ = wq[ky * 3 + kx];   // broadcast
              acc[o8][0] = fmaf(win[ky][kx],         wv_, acc[o8][0]);
              acc[o8][1] = fmaf(win[ky][kx + 1],     wv_, acc[o8][1]);
              acc[o8][2] = fmaf(win[ky + 1][kx],     wv_, acc[o8][2]);
              acc[o8][3] = fmaf(win[ky + 1][kx + 1], wv_, acc[o8][3]);
            }
        }
      }
#pragma unroll
      for (int o8 = 0; o8 < 8; o8++) {
        const int oc = half * 8 + o8;
        const float v = fmaxf(fmaxf(acc[o8][0], acc[o8][1]), fmaxf(acc[o8][2], acc[o8][3])) + sb[oc];
        out[(size_t)((b0 + bb) * 1152 + g * 16 + oc) * 81 + p] = fmaxf(v, 0.f);
      }
    }
  }
}

// ---------------- conv3: (64,1152,9,9) -> k3 (16->32) -> relu -> pool2 -> (64,2304,3,3)
#define C3_NBB 7
__global__ __launch_bounds__(256) void conv3_k(const float* __restrict__ x,
                                               const float* __restrict__ w,
                                               const float* __restrict__ bias,
                                               float* __restrict__ out) {
  const int g = blockIdx.x % NG, b0 = (blockIdx.x / NG) * C3_NBB;
  const int nbb = min(C3_NBB, 64 - b0);
  __shared__ float sx[C3_NBB][16][81];
  __shared__ float sw[32 * 16 * 9];
  __shared__ float sb[32];
  for (int bb = 0; bb < nbb; bb++) {
    const float* xp = x + (size_t)((b0 + bb) * 1152 + g * 16) * 81;
    for (int i = threadIdx.x; i < 16 * 81; i += 256) sx[bb][i / 81][i % 81] = xp[i];
  }
  const float* wp = w + (size_t)(g * 32) * 144;
  for (int i = threadIdx.x; i < 32 * 144; i += 256) sw[i] = wp[i];
  if (threadIdx.x < 32) sb[threadIdx.x] = bias[g * 32 + threadIdx.x];
  __syncthreads();
  for (int u = threadIdx.x; u < nbb * 36; u += 256) {
    const int bb = u / 36, rem = u % 36, ocg = rem / 9, p = rem % 9;
    const int py = p / 3, px = p % 3, iy = 2 * py, ix = 2 * px;
    float acc[8][4];
#pragma unroll
    for (int o = 0; o < 8; o++)
#pragma unroll
      for (int q = 0; q < 4; q++) acc[o][q] = 0.f;
#pragma unroll
    for (int ic = 0; ic < 16; ic++) {
      float win[4][4];
#pragma unroll
      for (int r = 0; r < 4; r++)
#pragma unroll
        for (int c = 0; c < 4; c++) win[r][c] = sx[bb][ic][(iy + r) * 9 + ix + c];
#pragma unroll
      for (int o8 = 0; o8 < 8; o8++) {
        const int oc = ocg * 8 + o8;
        const float* wq = &sw[(oc * 16 + ic) * 9];
#pragma unroll
        for (int ky = 0; ky < 3; ky++)
#pragma unroll
          for (int kx = 0; kx < 3; kx++) {
            const float wv_ = wq[ky * 3 + kx];   // broadcast
            acc[o8][0] = fmaf(win[ky][kx],         wv_, acc[o8][0]);
            acc[o8][1] = fmaf(win[ky][kx + 1],     wv_, acc[o8][1]);
            acc[o8][2] = fmaf(win[ky + 1][kx],     wv_, acc[o8][2]);
            acc[o8][3] = fmaf(win[ky + 1][kx + 1], wv_, acc[o8][3]);
          }
      }
    }
#pragma unroll
    for (int o8 = 0; o8 < 8; o8++) {
      const int oc = ocg * 8 + o8;
      const float v = fmaxf(fmaxf(acc[o8][0], acc[o8][1]), fmaxf(acc[o8][2], acc[o8][3])) + sb[oc];
      out[(size_t)((b0 + bb) * 2304 + g * 32 + oc) * 9 + p] = fmaxf(v, 0.f);
    }
  }
}

// ---------------- fused block-diagonal linear1 (288->64) + linear2 (64->2) + bias
__global__ __launch_bounds__(256) void lin_k(const float* __restrict__ h,
                                             const float* __restrict__ w1,
                                             const float* __restrict__ w2,
                                             const float* __restrict__ b2,
                                             float* __restrict__ out) {
  const int g = blockIdx.x % NG, b0 = (blockIdx.x / NG) * 32;
  __shared__ float sw1[64 * 292];
  __shared__ float sf[32 * 300];
  __shared__ float so[32 * 65];
  __shared__ float sw2[2 * 64];
  __shared__ float sb2[2];
  for (int i = threadIdx.x; i < 64 * 288; i += 256) {
    const int o = i / 288, k = i % 288;
    sw1[o * 292 + k] = w1[(size_t)(g * 64 + o) * 20736 + g * 288 + k];
  }
  for (int i = threadIdx.x; i < 32 * 288; i += 256) {
    const int bb = i / 288, k = i % 288;
    sf[bb * 300 + k] = h[(size_t)(b0 + bb) * 20736 + g * 288 + k];
  }
  if (threadIdx.x < 128) {
    const int j = threadIdx.x >> 6, o = threadIdx.x & 63;
    sw2[j * 64 + o] = w2[(size_t)(g * 2 + j) * 4608 + g * 64 + o];
  }
  if (threadIdx.x < 2) sb2[threadIdx.x] = b2[g * 2 + threadIdx.x];
  __syncthreads();
  const int bp = threadIdx.x & 15, oq = threadIdx.x >> 4;
  const int o0 = 4 * oq;
  float acc[2][4];
#pragma unroll
  for (int i = 0; i < 2; i++)
#pragma unroll
    for (int j = 0; j < 4; j++) acc[i][j] = 0.f;
  for (int k4 = 0; k4 < 72; k4++) {
    const float4 f0 = *(const float4*)&sf[bp * 300 + 4 * k4];
    const float4 f1 = *(const float4*)&sf[(bp + 16) * 300 + 4 * k4];
#pragma unroll
    for (int j = 0; j < 4; j++) {
      const float4 wr = *(const float4*)&sw1[(o0 + j) * 292 + 4 * k4];
      acc[0][j] = fmaf(f0.x, wr.x, fmaf(f0.y, wr.y, fmaf(f0.z, wr.z, fmaf(f0.w, wr.w, acc[0][j]))));
      acc[1][j] = fmaf(f1.x, wr.x, fmaf(f1.y, wr.y, fmaf(f1.z, wr.z, fmaf(f1.w, wr.w, acc[1][j]))));
    }
  }
#pragma unroll
  for (int j = 0; j < 4; j++) {
    so[bp * 65 + o0 + j] = acc[0][j];
    so[(bp + 16) * 65 + o0 + j] = acc[1][j];
  }
  __syncthreads();
  if (threadIdx.x < 64) {
    const int bb = threadIdx.x >> 1, j = threadIdx.x & 1;
    float a = sb2[j];
#pragma unroll 8
    for (int o = 0; o < 64; o++) a = fmaf(so[bb * 65 + o], sw2[j * 64 + o], a);
    out[(b0 + bb) * 144 + g * 2 + j] = a;
  }
}

extern "C" void kernel_launch(void* const* d_in, const int* in_sizes, int n_in,
                              void* d_out, int out_size, void* d_ws, size_t ws_size,
                              hipStream_t stream) {
  const float* x   = (const float*)d_in[0];
  const float* w1  = (const float*)d_in[1];
  const float* b1  = (const float*)d_in[2];
  const float* w2  = (const float*)d_in[3];
  const float* b2  = (const float*)d_in[4];
  const float* w3  = (const float*)d_in[5];
  const float* b3  = (const float*)d_in[6];
  const float* l1w = (const float*)d_in[7];
  const float* l2w = (const float*)d_in[8];
  const float* l2b = (const float*)d_in[9];
  float* out = (float*)d_out;

  float* h1 = (float*)d_ws;          // 64*576*21*21
  float* h2 = h1 + 16257024;         // 64*1152*9*9
  float* h3 = h2 + 5971968;          // 64*2304*3*3

  conv1_k<<<dim3(64 * NG), 448, 0, stream>>>(x,  w1, b1, h1);
  conv2_k<<<dim3(22 * NG), 256, 0, stream>>>(h1, w2, b2, h2);
  conv3_k<<<dim3(10 * NG), 256, 0, stream>>>(h2, w3, b3, h3);
  lin_k  <<<dim3(2 * NG),  256, 0, stream>>>(h3, l1w, l2w, l2b, out);
}